// Round 5
// baseline (9425.942 us; speedup 1.0000x reference)
//
#include <hip/hip_runtime.h>
#include <hip/hip_bf16.h>
#include <math.h>

typedef __bf16 bf16_t;
typedef __bf16 bf16x8 __attribute__((ext_vector_type(8)));
typedef float  f32x4  __attribute__((ext_vector_type(4)));

// ---------------- workspace layout (bytes) ----------------
#define WS_WSP    0        // 1297 f32
#define WS_AH     5248     // 256 f32
#define WS_U527   6272     // 527 f32
#define WS_BIAS   8384     // 1 f32
#define WS_BIASG  8448     // 1024 f32
#define WS_WC     12544    // 655360 B fragment-swizzled weights
#define WS_FLAGS  667904   // 64*4 int flags
#define WS_HBUF   669184   // 2*64*4*16384 bf16 = 16 MB h exchange (swizzled slices)

__device__ __forceinline__ float sigmoidf_fast(float x) {
    return 1.f / (1.f + __expf(-x));
}
__device__ __forceinline__ float tanhf_fast(float x) {
    // 1 - 2/(1+exp(2x)); saturates cleanly at +-1
    return 1.f - 2.f / (1.f + __expf(2.f * x));
}

// ---------------- head/spatial weight composition (tiny) ----------------
__global__ void k_head(const float* __restrict__ sl_w, const float* __restrict__ sl_b,
                       const float* __restrict__ st_w, const float* __restrict__ st_b,
                       const float* __restrict__ seg_b,
                       const float* __restrict__ l1_w, const float* __restrict__ l1_b,
                       const float* __restrict__ l2_w, const float* __restrict__ l2_b,
                       const float* __restrict__ l4_w, const float* __restrict__ l4_b,
                       const float* __restrict__ l5_w, const float* __restrict__ l5_b,
                       const float* __restrict__ l6_w, const float* __restrict__ l6_b,
                       const float* __restrict__ l7_w, const float* __restrict__ l7_b,
                       float* __restrict__ wsp, float* __restrict__ ah,
                       float* __restrict__ u527_out, float* __restrict__ bias_out) {
    __shared__ float v2[128], v3[256], aa[384], u256[256], u527[527];
    __shared__ float red[8];
    const int t = threadIdx.x;   // 512 threads

    if (t < 128) { float s = 0.f; for (int i = 0; i < 128; ++i) s += l7_w[i] * l6_w[i*128 + t]; v2[t] = s; }
    __syncthreads();
    if (t < 256) { float s = 0.f; for (int i = 0; i < 128; ++i) s += v2[i] * l5_w[i*256 + t]; v3[t] = s; }
    __syncthreads();
    if (t < 384) { float s = 0.f; for (int i = 0; i < 256; ++i) s += v3[i] * l4_w[i*384 + t]; aa[t] = s; }
    __syncthreads();
    if (t < 256) { float s = 0.f; for (int i = 0; i < 128; ++i) s += aa[i] * l2_w[i*256 + t]; u256[t] = s; }
    if (t < 256) ah[t] = aa[128 + t];
    __syncthreads();
    for (int j = t; j < 527; j += 512) {
        float s = 0.f;
        for (int i = 0; i < 256; ++i) s += u256[i] * l1_w[i*527 + j];
        u527[j] = s; u527_out[j] = s;
    }
    __syncthreads();
    if (t < 4)              { float s = 0.f; for (int i = 0; i < 2; ++i) s += u527[i]     * sl_w[i*4  + t];      wsp[t] = s; }
    else if (t < 16)        { int c = t - 4;  float s = 0.f; for (int i = 0; i < 8; ++i) s += u527[2+i] * st_w[i*12 + c]; wsp[t] = s; }
    else if (t < 21)        { wsp[1292 + (t - 16)] = u527[522 + (t - 16)]; }
    float p = 0.f;
    if (t < 128) p += l7_w[t] * l6_b[t] + v2[t] * l5_b[t] + aa[t] * l2_b[t];
    if (t < 256) p += v3[t] * l4_b[t] + u256[t] * l1_b[t];
    if (t < 2)   p += u527[t] * sl_b[t];
    if (t < 8)   p += u527[2 + t] * st_b[t];
    p += u527[10 + t] * seg_b[t];
    p += __shfl_xor(p, 1);  p += __shfl_xor(p, 2);  p += __shfl_xor(p, 4);
    p += __shfl_xor(p, 8);  p += __shfl_xor(p, 16); p += __shfl_xor(p, 32);
    if ((t & 63) == 0) red[t >> 6] = p;
    __syncthreads();
    if (t == 0) {
        float s = l7_b[0];
        for (int i = 0; i < 8; ++i) s += red[i];
        *bias_out = s;
    }
}

__global__ void k_seg(const float* __restrict__ seg_w, const float* __restrict__ u527,
                      float* __restrict__ wsp) {
    int j = blockIdx.x * 256 + threadIdx.x;
    if (j >= 1276) return;
    float s = 0.f;
    for (int i = 0; i < 512; ++i) s += u527[10 + i] * seg_w[i*1276 + j];
    wsp[16 + j] = s;
}

// fragment-swizzled combined weights (unchanged layout)
__global__ void k_wc(const float* __restrict__ w_ih, const float* __restrict__ b_ih,
                     const float* __restrict__ w_hh, const float* __restrict__ b_hh,
                     bf16_t* __restrict__ wc, float* __restrict__ biasg) {
    int idx = blockIdx.x * 256 + threadIdx.x;
    if (idx < 1024) biasg[idx] = b_ih[idx] + b_hh[idx];
    if (idx < 1024 * 320) {
        int e  = idx & 7;
        int l  = (idx >> 3) & 63;
        int t2 = idx >> 9;
        int kk = t2 % 10;
        int nt = t2 / 10;
        int n  = nt * 16 + (l & 15);
        int k  = kk * 32 + ((l >> 4) << 3) + e;
        float v = 0.f;
        if (k < 56)       v = w_ih[n*56 + k];
        else if (k >= 64) v = w_hh[n*256 + (k - 64)];
        wc[idx] = (bf16_t)v;
    }
}

__global__ void k_spatial(const float* __restrict__ sp, const float* __restrict__ wsp,
                          const float* __restrict__ bias, float* __restrict__ out) {
    int row  = blockIdx.x * 4 + (threadIdx.x >> 6);
    int lane = threadIdx.x & 63;
    const float* rp = sp + (size_t)row * 1297;
    float s = 0.f;
    for (int k = lane; k < 1297; k += 64) s += rp[k] * wsp[k];
    s += __shfl_xor(s, 1);  s += __shfl_xor(s, 2);  s += __shfl_xor(s, 4);
    s += __shfl_xor(s, 8);  s += __shfl_xor(s, 16); s += __shfl_xor(s, 32);
    if (lane == 0) out[row] = s + bias[0];
}

// ---------------- LSTM v5: weight-register-resident, 64 rg x 4 cg ----------------
// Block (rg = bid&63, cg = bid>>6): rows [rg*256, rg*256+256), hidden dims [cg*64, cg*64+64).
// 4 waves x 256 thr; wave w owns hd_local [16w,16w+16) for all 4 gates -> 40 bf16x8 = 160 VGPR weights.
// LDS Hs[4][256][64] bf16 (128 KiB): h(t-1), XOR-swizzled 16B slots per row (2-way free banks).
// Siblings exchange h via global hbuf (double-buffered by step parity) + step-stamped flags.
// x read from temporal (f32) with on-the-fly bf16 cvt.
__launch_bounds__(256, 1)
__global__ void k_lstm(const float* __restrict__ temporal, const bf16_t* __restrict__ wc,
                       const float* __restrict__ biasg, const float* __restrict__ ah,
                       bf16_t* __restrict__ hbuf, int* __restrict__ flags,
                       float* __restrict__ out) {
    __shared__ bf16_t Hs[4 * 256 * 64];          // 131072 B
    const int tid  = threadIdx.x;
    const int lane = tid & 63;
    const int w    = tid >> 6;                   // 0..3
    const int bid  = blockIdx.x;
    const int cg   = bid >> 6;                   // 0..3
    const int rg   = bid & 63;                   // 0..63
    const int l15  = lane & 15;
    const int l4q  = lane >> 4;                  // 0..3
    const int swzr = l15 & 7;                    // row&7 for A-read rows (row = ..16.. + l15)

    // ---- persistent weights: wf[q][kk], ntile = q*16 + cg*4 + w ----
    bf16x8 wf[4][10];
#pragma unroll
    for (int q = 0; q < 4; ++q)
#pragma unroll
        for (int kk = 0; kk < 10; ++kk) {
            int nt = q*16 + cg*4 + w;
            wf[q][kk] = *reinterpret_cast<const bf16x8*>(wc + ((size_t)(nt*10 + kk)*64 + lane)*8);
        }
#pragma unroll
    for (int q = 0; q < 4; ++q)
#pragma unroll
        for (int kk = 0; kk < 10; ++kk)
            asm volatile("" : "+v"(wf[q][kk]));   // block rematerialization

    const int hdl = 16*w + l15;                   // hidden dim (local 0..63)
    float bias[4];
#pragma unroll
    for (int q = 0; q < 4; ++q) bias[q] = biasg[q*256 + cg*64 + hdl];
    const float ahv = ah[cg*64 + hdl];

    // ---- zero LDS h (h_{-1} = 0) ----
    for (int i = tid; i < 32768; i += 256) reinterpret_cast<uint32_t*>(Hs)[i] = 0u;

    f32x4 cst[16];                                // c state: [p*4+rt][e]
#pragma unroll
    for (int i = 0; i < 16; ++i) cst[i] = (f32x4){0.f,0.f,0.f,0.f};
    f32x4 hsv[16];                                // h values (f32) of current step

    __syncthreads();

#pragma unroll 1
    for (int t = 0; t < 96; ++t) {
        // ---- ingest sibling h(t-1) slices ----
        if (t > 0) {
            if (tid < 3) {
                int sl = tid + (tid >= cg ? 1 : 0);
                while (__hip_atomic_load(&flags[rg*4 + sl], __ATOMIC_ACQUIRE,
                                         __HIP_MEMORY_SCOPE_AGENT) < t)
                    __builtin_amdgcn_s_sleep(1);
            }
            __syncthreads();
            int par = (t - 1) & 1;
            for (int i = w; i < 96; i += 4) {
                int j = i >> 5;                    // 0..2
                int sl = j + (j >= cg ? 1 : 0);
                int chunk = i & 31;                // 1 KB chunks
                const bf16_t* src = hbuf + (((par*64 + rg)*4 + sl) << 14) + (chunk << 9) + lane*8;
                __builtin_amdgcn_global_load_lds(
                    (const __attribute__((address_space(1))) uint32_t*)src,
                    (__attribute__((address_space(3))) uint32_t*)&Hs[(sl << 14) + (chunk << 9)],
                    16, 0, 0);
            }
            asm volatile("s_waitcnt vmcnt(0)" ::: "memory");
            __syncthreads();
        }

        // ---- 4 row-passes: MFMA + gates ----
#pragma unroll
        for (int p = 0; p < 4; ++p) {
            // x fragments (kk = 0,1) from global f32, cvt to bf16
            bf16x8 ax[4][2];
#pragma unroll
            for (int rt = 0; rt < 4; ++rt)
#pragma unroll
                for (int kk = 0; kk < 2; ++kk) {
                    bf16x8 v = (bf16x8){0,0,0,0,0,0,0,0};
                    if (!(kk == 1 && l4q == 3)) {
                        const float* xr = temporal
                            + (size_t)(rg*256 + p*64 + rt*16 + l15)*5376
                            + t*56 + kk*32 + l4q*8;
                        f32x4 a = *reinterpret_cast<const f32x4*>(xr);
                        f32x4 b = *reinterpret_cast<const f32x4*>(xr + 4);
#pragma unroll
                        for (int e = 0; e < 4; ++e) { v[e] = (bf16_t)a[e]; v[4+e] = (bf16_t)b[e]; }
                    }
                    ax[rt][kk] = v;
                }

            f32x4 acc[4][4];                       // [rowtile][gate]
#pragma unroll
            for (int rt = 0; rt < 4; ++rt)
#pragma unroll
                for (int q = 0; q < 4; ++q)
                    acc[rt][q] = (f32x4){bias[q], bias[q], bias[q], bias[q]};

#pragma unroll
            for (int kk = 0; kk < 10; ++kk) {
                bf16x8 af[4];
                if (kk < 2) {
#pragma unroll
                    for (int rt = 0; rt < 4; ++rt) af[rt] = ax[rt][kk];
                } else {
                    int hd0  = (kk - 2)*32 + l4q*8;         // 0..255
                    int sl   = hd0 >> 6;
                    int slot = (hd0 >> 3) & 7;
                    int off0 = (sl << 14) + ((slot ^ swzr) << 3);
#pragma unroll
                    for (int rt = 0; rt < 4; ++rt) {
                        int row = p*64 + rt*16 + l15;
                        af[rt] = *reinterpret_cast<const bf16x8*>(&Hs[off0 + row*64]);
                    }
                }
#pragma unroll
                for (int q = 0; q < 4; ++q)
#pragma unroll
                    for (int rt = 0; rt < 4; ++rt)
                        acc[rt][q] = __builtin_amdgcn_mfma_f32_16x16x32_bf16(
                            af[rt], wf[q][kk], acc[rt][q], 0, 0, 0);
            }

            // gates -> c, h (regs only; LDS untouched until barrier)
#pragma unroll
            for (int rt = 0; rt < 4; ++rt)
#pragma unroll
                for (int e = 0; e < 4; ++e) {
                    float ig = sigmoidf_fast(acc[rt][0][e]);
                    float fg = sigmoidf_fast(acc[rt][1][e]);
                    float gt = tanhf_fast(acc[rt][2][e]);
                    float og = sigmoidf_fast(acc[rt][3][e]);
                    float cn = fg * cst[p*4+rt][e] + ig * gt;
                    cst[p*4+rt][e] = cn;
                    hsv[p*4+rt][e] = og * tanhf_fast(cn);
                }
        }

        __syncthreads();   // all waves' LDS reads complete before own-slice overwrite

        // ---- write h(t): own LDS slice + global (swizzled) ----
        {
            int par = t & 1;
            bf16_t* gdst = hbuf + (((par*64 + rg)*4 + cg) << 14);
            const int wslot = hdl >> 3;
            const int hlow  = hdl & 7;
#pragma unroll
            for (int p = 0; p < 4; ++p)
#pragma unroll
                for (int rt = 0; rt < 4; ++rt)
#pragma unroll
                    for (int e = 0; e < 4; ++e) {
                        int row = p*64 + rt*16 + l4q*4 + e;
                        int off = row*64 + ((wslot ^ (row & 7)) << 3) + hlow;
                        bf16_t hv = (bf16_t)hsv[p*4+rt][e];
                        Hs[(cg << 14) + off] = hv;
                        gdst[off] = hv;
                    }
        }
        __threadfence();
        __syncthreads();
        if (tid == 0)
            __hip_atomic_store(&flags[rg*4 + cg], t + 1, __ATOMIC_RELEASE,
                               __HIP_MEMORY_SCOPE_AGENT);
    }

    // ---- epilogue: out[row] += sum_{hd in block} ah[hd] * h_T[row][hd] ----
#pragma unroll
    for (int p = 0; p < 4; ++p)
#pragma unroll
        for (int rt = 0; rt < 4; ++rt)
#pragma unroll
            for (int e = 0; e < 4; ++e) {
                float s = ahv * hsv[p*4+rt][e];
                s += __shfl_xor(s, 1); s += __shfl_xor(s, 2);
                s += __shfl_xor(s, 4); s += __shfl_xor(s, 8);
                if (l15 == 0)
                    atomicAdd(&out[rg*256 + p*64 + rt*16 + l4q*4 + e], s);
            }
}

// ---------------- launch ----------------
extern "C" void kernel_launch(void* const* d_in, const int* in_sizes, int n_in,
                              void* d_out, int out_size, void* d_ws, size_t ws_size,
                              hipStream_t stream) {
    const float* spatial  = (const float*)d_in[0];
    const float* temporal = (const float*)d_in[1];
    const float* sl_w = (const float*)d_in[2];  const float* sl_b = (const float*)d_in[3];
    const float* st_w = (const float*)d_in[4];  const float* st_b = (const float*)d_in[5];
    const float* seg_w = (const float*)d_in[6]; const float* seg_b = (const float*)d_in[7];
    const float* l1_w = (const float*)d_in[8];  const float* l1_b = (const float*)d_in[9];
    const float* l2_w = (const float*)d_in[10]; const float* l2_b = (const float*)d_in[11];
    const float* w_ih = (const float*)d_in[12]; const float* b_ih = (const float*)d_in[13];
    const float* w_hh = (const float*)d_in[14]; const float* b_hh = (const float*)d_in[15];
    const float* l4_w = (const float*)d_in[16]; const float* l4_b = (const float*)d_in[17];
    const float* l5_w = (const float*)d_in[18]; const float* l5_b = (const float*)d_in[19];
    const float* l6_w = (const float*)d_in[20]; const float* l6_b = (const float*)d_in[21];
    const float* l7_w = (const float*)d_in[22]; const float* l7_b = (const float*)d_in[23];

    char* ws = (char*)d_ws;
    float*  wsp   = (float*)(ws + WS_WSP);
    float*  ah    = (float*)(ws + WS_AH);
    float*  u527  = (float*)(ws + WS_U527);
    float*  biasT = (float*)(ws + WS_BIAS);
    float*  biasg = (float*)(ws + WS_BIASG);
    bf16_t* wc    = (bf16_t*)(ws + WS_WC);
    int*    flags = (int*)(ws + WS_FLAGS);
    bf16_t* hbuf  = (bf16_t*)(ws + WS_HBUF);

    float* out = (float*)d_out;

    hipMemsetAsync(flags, 0, 64*4*sizeof(int), stream);

    hipLaunchKernelGGL(k_head, dim3(1), dim3(512), 0, stream,
                       sl_w, sl_b, st_w, st_b, seg_b, l1_w, l1_b, l2_w, l2_b,
                       l4_w, l4_b, l5_w, l5_b, l6_w, l6_b, l7_w, l7_b,
                       wsp, ah, u527, biasT);
    hipLaunchKernelGGL(k_seg, dim3(5), dim3(256), 0, stream, seg_w, u527, wsp);
    hipLaunchKernelGGL(k_wc, dim3((1024*320 + 255)/256), dim3(256), 0, stream,
                       w_ih, b_ih, w_hh, b_hh, wc, biasg);
    hipLaunchKernelGGL(k_spatial, dim3(16384/4), dim3(256), 0, stream,
                       spatial, wsp, biasT, out);
    hipLaunchKernelGGL(k_lstm, dim3(256), dim3(256), 0, stream,
                       temporal, wc, biasg, ah, hbuf, flags, out);
}